// Round 6
// baseline (36.697 us; speedup 1.0000x reference)
//
#include <hip/hip_runtime.h>
#include <math.h>

// KDE Gaussian, bandwidth 0.1:
//   out[b,m] = sum_n exp(-50*||s[b,n]-l[m]||^2), normalized per batch.
// exp(-50 d2) = exp2(W*d2), W = -50*log2(e).  Terms with t <= -14 dropped
// (integrated dropped mass ~1e-7 normalized vs 9.4e-6 threshold).
// Dispatch-floor aware design (~30cy/workgroup): only 512 fat main blocks.
//   - 1024-sample segments counting-sorted into 16x16 MORTON bins (compact
//     2-D chunks, not strips) in one fused prepass
//   - block = (batch, 16x16-pt tile, half): loops 8 chunks, one parallel
//     8-way chunk test (__ballot), stages only passing chunks into LDS
//   - per-4-sample group bounding circle; 64 parallel tests -> __ballot
//   - accumulators live in registers across chunks; 1 atomic per point-half
// Triangle inequality with conservative radii keeps culling exact-enough.

#define W_CONST  (-72.13475204444817f)   // -50 * log2(e)
#define RCUT     0.44060f                // d > RCUT => t <= -14 => dropped
#define PR       0.23400f                // 8x8-point wave patch half-diag + margin
#define TILE_R   0.50200f                // 16x16-point tile half-diag + margin

constexpr int Bc = 4, Nc = 4096, Mc = 128 * 128, Wg = 128;
constexpr int SEG = 1024, NSEG = 16;     // 16 sort segments (4/batch)
constexpr int GPC = 64;                  // groups/chunk = exactly 1 ballot
constexpr float Hh = 6.0f / 127.0f;      // grid spacing

typedef float f2 __attribute__((ext_vector_type(2)));

__device__ __forceinline__ float fexp2(float x) {
#if __has_builtin(__builtin_amdgcn_exp2f)
    return __builtin_amdgcn_exp2f(x);        // raw v_exp_f32
#else
    float r; asm("v_exp_f32 %0, %1" : "=v"(r) : "v"(x)); return r;
#endif
}
__device__ __forceinline__ f2 pkfma(f2 a, f2 b, f2 c) {
    return __builtin_elementwise_fma(a, b, c);   // v_pk_fma_f32
}

// Morton (Z-order) bin index: compact 2-D locality for sorted chunks.
__device__ __forceinline__ int bin_of(float x, float y) {
    int ix = (int)((x + 3.0f) * (16.0f / 6.0f));
    int iy = (int)((y + 3.0f) * (16.0f / 6.0f));
    ix = ix < 0 ? 0 : (ix > 15 ? 15 : ix);
    iy = iy < 0 ? 0 : (iy > 15 ? 15 : iy);
    ix = (ix | (ix << 2)) & 0x33; ix = (ix | (ix << 1)) & 0x55;
    iy = (iy | (iy << 2)) & 0x33; iy = (iy | (iy << 1)) & 0x55;
    return ix | (iy << 1);
}

// One block per 1024-sample segment: LDS counting sort + group/chunk metadata
// + packed-SoA writeback + zeroing of out/norm.
__global__ __launch_bounds__(1024) void prep(
        const float2* __restrict__ samples, float4* __restrict__ pk,
        float4* __restrict__ gmeta, float4* __restrict__ cmeta,
        float* __restrict__ out, float* __restrict__ norm) {
    __shared__ int cnt[256];
    __shared__ int cur[256];
    __shared__ float4 sorted[SEG];   // 16 KB

    const int s = blockIdx.x;        // segment id
    const int t = threadIdx.x;

    ((float4*)out)[s * 1024 + t] = make_float4(0.f, 0.f, 0.f, 0.f);
    if (s == 0 && t < Bc) norm[t] = 0.0f;
    if (t < 256) cnt[t] = 0;
    __syncthreads();

    const float2 v = samples[s * SEG + t];
    const int bin = bin_of(v.x, v.y);
    atomicAdd(&cnt[bin], 1);
    __syncthreads();

    // Single-wave exclusive scan over 256 bins: 4 bins/lane + shfl_up scan.
    if (t < 64) {
        const int c0 = cnt[4 * t], c1 = cnt[4 * t + 1];
        const int c2 = cnt[4 * t + 2], c3 = cnt[4 * t + 3];
        const int s0 = c0, s1 = s0 + c1, s2 = s1 + c2, s3 = s2 + c3;
        int scan = s3;
#pragma unroll
        for (int off = 1; off < 64; off <<= 1) {
            const int u = __shfl_up(scan, off, 64);
            if (t >= off) scan += u;
        }
        const int prefix = scan - s3;    // exclusive over lanes
        cur[4 * t]     = prefix;
        cur[4 * t + 1] = prefix + s0;
        cur[4 * t + 2] = prefix + s1;
        cur[4 * t + 3] = prefix + s2;
    }
    __syncthreads();

    const int pos = atomicAdd(&cur[bin], 1);
    sorted[pos] = make_float4(v.x, v.y, W_CONST * (v.x * v.x + v.y * v.y), 0.f);
    __syncthreads();

    if (t < 256) {                           // group = 4 sorted samples
        const float4* g = &sorted[4 * t];
        const float4 s0 = g[0], s1 = g[1], s2 = g[2], s3 = g[3];

        // packed float2-SoA: A=[x01|y01] B=[z01|x23] C=[y23|z23]
        const int base = (s * 256 + t) * 3;
        pk[base + 0] = make_float4(s0.x, s1.x, s0.y, s1.y);
        pk[base + 1] = make_float4(s0.z, s1.z, s2.x, s3.x);
        pk[base + 2] = make_float4(s2.y, s3.y, s2.z, s3.z);

        float mnx = fminf(fminf(s0.x, s1.x), fminf(s2.x, s3.x));
        float mxx = fmaxf(fmaxf(s0.x, s1.x), fmaxf(s2.x, s3.x));
        float mny = fminf(fminf(s0.y, s1.y), fminf(s2.y, s3.y));
        float mxy = fmaxf(fmaxf(s0.y, s1.y), fmaxf(s2.y, s3.y));
        float ex = 0.5f * (mxx - mnx), ey = 0.5f * (mxy - mny);
        float r = sqrtf(ex * ex + ey * ey);
        gmeta[s * 256 + t] =
            make_float4(0.5f * (mnx + mxx), 0.5f * (mny + mxy), RCUT + r, r);

        // chunk meta: 64 groups = one wave; butterfly min/max reduce
        float cmnx = mnx, cmxx = mxx, cmny = mny, cmxy = mxy;
#pragma unroll
        for (int off = 1; off < 64; off <<= 1) {
            cmnx = fminf(cmnx, __shfl_xor(cmnx, off, 64));
            cmxx = fmaxf(cmxx, __shfl_xor(cmxx, off, 64));
            cmny = fminf(cmny, __shfl_xor(cmny, off, 64));
            cmxy = fmaxf(cmxy, __shfl_xor(cmxy, off, 64));
        }
        if ((t & 63) == 0) {
            float cex = 0.5f * (cmxx - cmnx), cey = 0.5f * (cmxy - cmny);
            cmeta[s * 4 + (t >> 6)] =
                make_float4(0.5f * (cmnx + cmxx), 0.5f * (cmny + cmxy),
                            RCUT + sqrtf(cex * cex + cey * cey), 0.f);
        }
    }
}

// Block = (batch, 16x16-point tile, chunk-half). 1 point/lane; each block
// loops over its 8 chunks, staging only passing ones into LDS.
__global__ __launch_bounds__(256) void kde_main(
        const float4* __restrict__ pk, const float4* __restrict__ gmeta,
        const float4* __restrict__ cmeta,
        float* __restrict__ out, float* __restrict__ norm) {
    const int bid  = blockIdx.x;
    const int tile = bid & 63;               // fastest: spread across XCDs
    const int b    = (bid >> 6) & 3;
    const int q    = bid >> 8;               // chunk half: 0 or 1
    const int ti = tile >> 3, tj = tile & 7;
    const int tid = threadIdx.x;
    const int wave = tid >> 6, lane = tid & 63;

    // 8 chunk-vs-tile tests in parallel (lanes 0-7) -> block-uniform mask.
    const float tcx = -3.0f + ((float)(ti * 16) + 7.5f) * Hh;
    const float tcy = -3.0f + ((float)(tj * 16) + 7.5f) * Hh;
    const float4 cmv = cmeta[b * 16 + q * 8 + (lane & 7)];
    const float cdx = tcx - cmv.x, cdy = tcy - cmv.y;
    const float crr = cmv.z + TILE_R;
    const unsigned long long cb =
        __ballot((lane < 8) && (cdx * cdx + cdy * cdy <= crr * crr));
    unsigned cmask = (unsigned)(cb & 0xFFu);
    if (!cmask) return;

    __shared__ float4 sh4[GPC * 3];   // 3 KB packed groups
    __shared__ float4 gm[GPC];        // 1 KB group metas
    __shared__ float wred[4];

    const int wi = wave >> 1, wj = wave & 1;
    const int gi = ti * 16 + wi * 8 + (lane >> 3);
    const int gj = tj * 16 + wj * 8 + (lane & 7);
    const int m = gi * Wg + gj;

    const float lx = (float)(-3.0 + gi * (6.0 / 127.0));   // analytic grid
    const float ly = (float)(-3.0 + gj * (6.0 / 127.0));
    const f2 axv = (f2)(-2.0f * W_CONST * lx);
    const f2 ayv = (f2)(-2.0f * W_CONST * ly);
    const f2 c0v = (f2)(W_CONST * (lx * lx + ly * ly));
    const float pcx = -3.0f + ((float)(ti * 16 + wi * 8) + 3.5f) * Hh;
    const float pcy = -3.0f + ((float)(tj * 16 + wj * 8) + 3.5f) * Hh;

    float a0 = 0.f, a1 = 0.f, a2 = 0.f, a3 = 0.f;
    while (cmask) {
        const int c = __builtin_ctz(cmask);
        cmask &= cmask - 1;
        const int gb = b * 1024 + (q * 8 + c) * GPC;   // first group of chunk
        if (tid < 192) sh4[tid] = pk[gb * 3 + tid];
        else           gm[tid - 192] = gmeta[gb + tid - 192];
        __syncthreads();

        // 64 group tests in parallel -> wave-uniform bitmask.
        const float4 gv = gm[lane];
        const float gdx = pcx - gv.x, gdy = pcy - gv.y;
        const float grr = gv.z + PR;
        unsigned long long gmask =
            __ballot(gdx * gdx + gdy * gdy <= grr * grr);
        while (gmask) {
            const int g = __builtin_ctzll(gmask);
            gmask &= gmask - 1;
            const float4 A = sh4[3 * g + 0];   // broadcast reads
            const float4 B = sh4[3 * g + 1];
            const float4 C = sh4[3 * g + 2];
            const f2 x01 = {A.x, A.y}, y01 = {A.z, A.w};
            const f2 z01 = {B.x, B.y}, x23 = {B.z, B.w};
            const f2 y23 = {C.x, C.y}, z23 = {C.z, C.w};
            const f2 t01 = pkfma(axv, x01, pkfma(ayv, y01, z01) + c0v);
            const f2 t23 = pkfma(axv, x23, pkfma(ayv, y23, z23) + c0v);
            a0 += fexp2(t01.x); a1 += fexp2(t01.y);
            a2 += fexp2(t23.x); a3 += fexp2(t23.y);
        }
        __syncthreads();   // before next chunk overwrites LDS
    }

    const float acc = (a0 + a1) + (a2 + a3);
    if (acc != 0.0f) atomicAdd(&out[b * Mc + m], acc);

    float v = acc;
#pragma unroll
    for (int off = 32; off > 0; off >>= 1) v += __shfl_down(v, off, 64);
    if (lane == 0) wred[wave] = v;
    __syncthreads();
    if (tid == 0) {
        float tsum = (wred[0] + wred[1]) + (wred[2] + wred[3]);
        if (tsum != 0.0f) atomicAdd(&norm[b], tsum);
    }
}

__global__ __launch_bounds__(256) void kde_norm(float4* __restrict__ out,
                                                const float* __restrict__ norm) {
    const int i = blockIdx.x * 256 + threadIdx.x;   // float4 index
    const float inv = 1.0f / norm[i >> 12];         // Mc/4 = 4096 per batch
    float4 v = out[i];
    v.x *= inv; v.y *= inv; v.z *= inv; v.w *= inv;
    out[i] = v;
}

extern "C" void kernel_launch(void* const* d_in, const int* in_sizes, int n_in,
                              void* d_out, int out_size, void* d_ws, size_t ws_size,
                              hipStream_t stream) {
    const float* samples = (const float*)d_in[0];   // (B, N, 2) fp32
    float* out = (float*)d_out;                     // (B, H, W) fp32

    char* ws = (char*)d_ws;
    float4* pk    = (float4*)(ws);                  // 4096 groups * 48 B
    float4* gmeta = (float4*)(ws + 196608);         //  65536 B
    float4* cmeta = (float4*)(ws + 262144);         //   1024 B
    float*  norm  = (float*)(ws + 263168);          //     16 B

    prep    <<<NSEG, 1024, 0, stream>>>((const float2*)samples, pk,
                                        gmeta, cmeta, out, norm);
    kde_main<<<512, 256, 0, stream>>>(pk, gmeta, cmeta, out, norm);
    kde_norm<<<Bc * Mc / 4 / 256, 256, 0, stream>>>((float4*)out, norm);
}

// Round 7
// 32.555 us; speedup vs baseline: 1.1272x; 1.1272x over previous
//
#include <hip/hip_runtime.h>
#include <math.h>

// KDE Gaussian, bandwidth 0.1:
//   out[b,m] = sum_n exp(-50*||s[b,n]-l[m]||^2), normalized per batch.
// exp(-50 d2) = exp2(W*d2), W = -50*log2(e).  Terms with t <= -14 dropped
// (integrated dropped mass ~1e-7 normalized vs 9.4e-6 threshold).
// Worst-WAVE-latency aware design: block = (batch, 16x16-pt tile, half).
//   - stage ALL 8 chunks of the half (32 KB) in one burst + ONE barrier;
//     LDS read-only afterwards -> no per-chunk sync convoy
//   - per-chunk 64-group ballot; ctz loop UNROLLED x2 with dual prefetch
//     (6 independent ds_read_b128 in flight -> ~65 cy/iter instead of ~130)
//   - odd tail handled branchlessly: force t=-1000 -> exp2(t)=0 exactly
//   - 1024-sample segments counting-sorted into Morton bins (fused prepass)

#define W_CONST  (-72.13475204444817f)   // -50 * log2(e)
#define RCUT     0.44060f                // d > RCUT => t <= -14 => dropped
#define PR       0.23400f                // 8x8-point wave patch half-diag + margin
#define TILE_R   0.50200f                // 16x16-point tile half-diag + margin

constexpr int Bc = 4, Nc = 4096, Mc = 128 * 128, Wg = 128;
constexpr int SEG = 1024, NSEG = 16;     // 16 sort segments (4/batch)
constexpr float Hh = 6.0f / 127.0f;      // grid spacing

typedef float f2 __attribute__((ext_vector_type(2)));

__device__ __forceinline__ float fexp2(float x) {
#if __has_builtin(__builtin_amdgcn_exp2f)
    return __builtin_amdgcn_exp2f(x);        // raw v_exp_f32
#else
    float r; asm("v_exp_f32 %0, %1" : "=v"(r) : "v"(x)); return r;
#endif
}
__device__ __forceinline__ f2 pkfma(f2 a, f2 b, f2 c) {
    return __builtin_elementwise_fma(a, b, c);   // v_pk_fma_f32
}

// Morton (Z-order) bin index: compact 2-D locality for sorted chunks.
__device__ __forceinline__ int bin_of(float x, float y) {
    int ix = (int)((x + 3.0f) * (16.0f / 6.0f));
    int iy = (int)((y + 3.0f) * (16.0f / 6.0f));
    ix = ix < 0 ? 0 : (ix > 15 ? 15 : ix);
    iy = iy < 0 ? 0 : (iy > 15 ? 15 : iy);
    ix = (ix | (ix << 2)) & 0x33; ix = (ix | (ix << 1)) & 0x55;
    iy = (iy | (iy << 2)) & 0x33; iy = (iy | (iy << 1)) & 0x55;
    return ix | (iy << 1);
}

// One block per 1024-sample segment: LDS counting sort + group/chunk metadata
// + packed-SoA writeback + zeroing of out/norm.
__global__ __launch_bounds__(1024) void prep(
        const float2* __restrict__ samples, float4* __restrict__ pk,
        float4* __restrict__ gmeta, float4* __restrict__ cmeta,
        float* __restrict__ out, float* __restrict__ norm) {
    __shared__ int cnt[256];
    __shared__ int cur[256];
    __shared__ float4 sorted[SEG];   // 16 KB

    const int s = blockIdx.x;        // segment id
    const int t = threadIdx.x;

    ((float4*)out)[s * 1024 + t] = make_float4(0.f, 0.f, 0.f, 0.f);
    if (s == 0 && t < Bc) norm[t] = 0.0f;
    if (t < 256) cnt[t] = 0;
    __syncthreads();

    const float2 v = samples[s * SEG + t];
    const int bin = bin_of(v.x, v.y);
    atomicAdd(&cnt[bin], 1);
    __syncthreads();

    // Single-wave exclusive scan over 256 bins: 4 bins/lane + shfl_up scan.
    if (t < 64) {
        const int c0 = cnt[4 * t], c1 = cnt[4 * t + 1];
        const int c2 = cnt[4 * t + 2], c3 = cnt[4 * t + 3];
        const int s0 = c0, s1 = s0 + c1, s2 = s1 + c2, s3 = s2 + c3;
        int scan = s3;
#pragma unroll
        for (int off = 1; off < 64; off <<= 1) {
            const int u = __shfl_up(scan, off, 64);
            if (t >= off) scan += u;
        }
        const int prefix = scan - s3;    // exclusive over lanes
        cur[4 * t]     = prefix;
        cur[4 * t + 1] = prefix + s0;
        cur[4 * t + 2] = prefix + s1;
        cur[4 * t + 3] = prefix + s2;
    }
    __syncthreads();

    const int pos = atomicAdd(&cur[bin], 1);
    sorted[pos] = make_float4(v.x, v.y, W_CONST * (v.x * v.x + v.y * v.y), 0.f);
    __syncthreads();

    if (t < 256) {                           // group = 4 sorted samples
        const float4* g = &sorted[4 * t];
        const float4 s0 = g[0], s1 = g[1], s2 = g[2], s3 = g[3];

        // packed float2-SoA: A=[x01|y01] B=[z01|x23] C=[y23|z23]
        const int base = (s * 256 + t) * 3;
        pk[base + 0] = make_float4(s0.x, s1.x, s0.y, s1.y);
        pk[base + 1] = make_float4(s0.z, s1.z, s2.x, s3.x);
        pk[base + 2] = make_float4(s2.y, s3.y, s2.z, s3.z);

        float mnx = fminf(fminf(s0.x, s1.x), fminf(s2.x, s3.x));
        float mxx = fmaxf(fmaxf(s0.x, s1.x), fmaxf(s2.x, s3.x));
        float mny = fminf(fminf(s0.y, s1.y), fminf(s2.y, s3.y));
        float mxy = fmaxf(fmaxf(s0.y, s1.y), fmaxf(s2.y, s3.y));
        float ex = 0.5f * (mxx - mnx), ey = 0.5f * (mxy - mny);
        float r = sqrtf(ex * ex + ey * ey);
        gmeta[s * 256 + t] =
            make_float4(0.5f * (mnx + mxx), 0.5f * (mny + mxy), RCUT + r, r);

        // chunk meta: 64 groups = one wave; butterfly min/max reduce
        float cmnx = mnx, cmxx = mxx, cmny = mny, cmxy = mxy;
#pragma unroll
        for (int off = 1; off < 64; off <<= 1) {
            cmnx = fminf(cmnx, __shfl_xor(cmnx, off, 64));
            cmxx = fmaxf(cmxx, __shfl_xor(cmxx, off, 64));
            cmny = fminf(cmny, __shfl_xor(cmny, off, 64));
            cmxy = fmaxf(cmxy, __shfl_xor(cmxy, off, 64));
        }
        if ((t & 63) == 0) {
            float cex = 0.5f * (cmxx - cmnx), cey = 0.5f * (cmxy - cmny);
            cmeta[s * 4 + (t >> 6)] =
                make_float4(0.5f * (cmnx + cmxx), 0.5f * (cmny + cmxy),
                            RCUT + sqrtf(cex * cex + cey * cey), 0.f);
        }
    }
}

// Block = (batch, 16x16-point tile, half). Stages 8 chunks (512 groups) once,
// then loops chunks with zero further barriers.
__global__ __launch_bounds__(256) void kde_main(
        const float4* __restrict__ pk, const float4* __restrict__ gmeta,
        const float4* __restrict__ cmeta,
        float* __restrict__ out, float* __restrict__ norm) {
    const int bid  = blockIdx.x;
    const int tile = bid & 63;               // fastest: spread across XCDs
    const int b    = (bid >> 6) & 3;
    const int h    = bid >> 8;               // half: chunks h*8 .. h*8+7
    const int ti = tile >> 3, tj = tile & 7;
    const int tid = threadIdx.x;
    const int wave = tid >> 6, lane = tid & 63;

    // 8 chunk-vs-tile tests in parallel (lanes 0-7) -> block early-exit.
    const float tcx = -3.0f + ((float)(ti * 16) + 7.5f) * Hh;
    const float tcy = -3.0f + ((float)(tj * 16) + 7.5f) * Hh;
    const float4 cmv = cmeta[b * 16 + h * 8 + (lane & 7)];
    const float cdx = tcx - cmv.x, cdy = tcy - cmv.y;
    const float crr = cmv.z + TILE_R;
    const unsigned long long cb =
        __ballot((lane < 8) && (cdx * cdx + cdy * cdy <= crr * crr));
    if ((cb & 0xFFull) == 0) return;

    __shared__ float4 sh4[1536];   // 24 KB: 512 packed groups
    __shared__ float4 gm[512];     //  8 KB: group metas
    __shared__ float wred[4];

    // Stage the whole half-batch in one burst (8 independent loads/thread).
    const int gbase = b * 1024 + h * 512;
#pragma unroll
    for (int i = 0; i < 6; ++i)
        sh4[tid + 256 * i] = pk[gbase * 3 + tid + 256 * i];
#pragma unroll
    for (int i = 0; i < 2; ++i)
        gm[tid + 256 * i] = gmeta[gbase + tid + 256 * i];

    const int wi = wave >> 1, wj = wave & 1;
    const int gi = ti * 16 + wi * 8 + (lane >> 3);
    const int gj = tj * 16 + wj * 8 + (lane & 7);
    const int m = gi * Wg + gj;

    const float lx = (float)(-3.0 + gi * (6.0 / 127.0));   // analytic grid
    const float ly = (float)(-3.0 + gj * (6.0 / 127.0));
    const f2 axv = (f2)(-2.0f * W_CONST * lx);
    const f2 ayv = (f2)(-2.0f * W_CONST * ly);
    const f2 c0v = (f2)(W_CONST * (lx * lx + ly * ly));
    const float pcx = -3.0f + ((float)(ti * 16 + wi * 8) + 3.5f) * Hh;
    const float pcy = -3.0f + ((float)(tj * 16 + wj * 8) + 3.5f) * Hh;

    __syncthreads();   // the ONLY barrier; LDS is read-only from here

    float a0 = 0.f, a1 = 0.f, a2 = 0.f, a3 = 0.f;
    for (int c = 0; c < 8; ++c) {
        // 64 group tests in parallel -> wave-uniform bitmask for this chunk.
        const float4 gv = gm[c * 64 + lane];
        const float gdx = pcx - gv.x, gdy = pcy - gv.y;
        const float grr = gv.z + PR;
        unsigned long long gmask =
            __ballot(gdx * gdx + gdy * gdy <= grr * grr);

        while (gmask) {
            const int g0 = c * 64 + __builtin_ctzll(gmask);
            gmask &= gmask - 1;
            const bool has1 = (gmask != 0);
            int g1 = g0;
            if (has1) { g1 = c * 64 + __builtin_ctzll(gmask); gmask &= gmask - 1; }
            // 6 independent LDS broadcast loads in flight together.
            const float4 A0 = sh4[3 * g0 + 0];
            const float4 B0 = sh4[3 * g0 + 1];
            const float4 C0 = sh4[3 * g0 + 2];
            const float4 A1 = sh4[3 * g1 + 0];
            const float4 B1 = sh4[3 * g1 + 1];
            const float4 C1 = sh4[3 * g1 + 2];
            const f2 x01a = {A0.x, A0.y}, y01a = {A0.z, A0.w};
            const f2 z01a = {B0.x, B0.y}, x23a = {B0.z, B0.w};
            const f2 y23a = {C0.x, C0.y}, z23a = {C0.z, C0.w};
            f2 t01a = pkfma(axv, x01a, pkfma(ayv, y01a, z01a) + c0v);
            f2 t23a = pkfma(axv, x23a, pkfma(ayv, y23a, z23a) + c0v);
            const f2 x01b = {A1.x, A1.y}, y01b = {A1.z, A1.w};
            const f2 z01b = {B1.x, B1.y}, x23b = {B1.z, B1.w};
            const f2 y23b = {C1.x, C1.y}, z23b = {C1.z, C1.w};
            f2 t01b = pkfma(axv, x01b, pkfma(ayv, y01b, z01b) + c0v);
            f2 t23b = pkfma(axv, x23b, pkfma(ayv, y23b, z23b) + c0v);
            if (!has1) { t01b = (f2)(-1000.0f); t23b = (f2)(-1000.0f); }
            a0 += fexp2(t01a.x); a1 += fexp2(t01a.y);
            a2 += fexp2(t23a.x); a3 += fexp2(t23a.y);
            a0 += fexp2(t01b.x); a1 += fexp2(t01b.y);
            a2 += fexp2(t23b.x); a3 += fexp2(t23b.y);
        }
    }

    const float acc = (a0 + a1) + (a2 + a3);
    if (acc != 0.0f) atomicAdd(&out[b * Mc + m], acc);

    float v = acc;
#pragma unroll
    for (int off = 32; off > 0; off >>= 1) v += __shfl_down(v, off, 64);
    if (lane == 0) wred[wave] = v;
    __syncthreads();
    if (tid == 0) {
        float tsum = (wred[0] + wred[1]) + (wred[2] + wred[3]);
        if (tsum != 0.0f) atomicAdd(&norm[b], tsum);
    }
}

__global__ __launch_bounds__(256) void kde_norm(float4* __restrict__ out,
                                                const float* __restrict__ norm) {
    const int i = blockIdx.x * 256 + threadIdx.x;   // float4 index
    const float inv = 1.0f / norm[i >> 12];         // Mc/4 = 4096 per batch
    float4 v = out[i];
    v.x *= inv; v.y *= inv; v.z *= inv; v.w *= inv;
    out[i] = v;
}

extern "C" void kernel_launch(void* const* d_in, const int* in_sizes, int n_in,
                              void* d_out, int out_size, void* d_ws, size_t ws_size,
                              hipStream_t stream) {
    const float* samples = (const float*)d_in[0];   // (B, N, 2) fp32
    float* out = (float*)d_out;                     // (B, H, W) fp32

    char* ws = (char*)d_ws;
    float4* pk    = (float4*)(ws);                  // 4096 groups * 48 B
    float4* gmeta = (float4*)(ws + 196608);         //  65536 B
    float4* cmeta = (float4*)(ws + 262144);         //   1024 B
    float*  norm  = (float*)(ws + 263168);          //     16 B

    prep    <<<NSEG, 1024, 0, stream>>>((const float2*)samples, pk,
                                        gmeta, cmeta, out, norm);
    kde_main<<<512, 256, 0, stream>>>(pk, gmeta, cmeta, out, norm);
    kde_norm<<<Bc * Mc / 4 / 256, 256, 0, stream>>>((float4*)out, norm);
}